// Round 2
// baseline (367.606 us; speedup 1.0000x reference)
//
#include <hip/hip_runtime.h>

typedef __bf16 bf16_t;
typedef __bf16 bf16x4 __attribute__((ext_vector_type(4)));
typedef __bf16 bf16x8 __attribute__((ext_vector_type(8)));
typedef float f32x4 __attribute__((ext_vector_type(4)));

constexpr int TT = 2048;
constexpr int DDIM = 1024;

// workspace layout (bf16 element offsets)
constexpr size_t SZ_TD  = (size_t)2048 * 1024;   // 2,097,152 elems = one [T][D] plane
constexpr size_t OFF_QU = 0;                     // Qu[h][t][dh] = q + u
constexpr size_t OFF_QV = 1 * SZ_TD;             // Qv[h][t][dh] = q + v_bias
constexpr size_t OFF_KK = 2 * SZ_TD;             // K [h][t][dh]
constexpr size_t OFF_RR = 3 * SZ_TD;             // Rrev[h][c][dh] = R[T-1-c]
constexpr size_t OFF_VT = 4 * SZ_TD;             // Vt[h][dh][t]
constexpr size_t OFF_AO = 5 * SZ_TD;             // attnout[t][d]
constexpr size_t OFF_XB = 6 * SZ_TD;             // x bf16 [t][d]
constexpr size_t OFF_RB = 7 * SZ_TD;             // r_emb bf16 [t][d]
constexpr size_t OFF_WT = 8 * SZ_TD;             // Wt[5][n][k] bf16 (q,k,v,r,o)
constexpr size_t SZ_W   = (size_t)1024 * 1024;

__device__ __forceinline__ f32x4 fzero4() {
  f32x4 z; z[0] = 0.f; z[1] = 0.f; z[2] = 0.f; z[3] = 0.f; return z;
}

// ---------------- prep 1: fp32 -> bf16 for x and r_emb ----------------
__global__ __launch_bounds__(256) void convert_kernel(const float* __restrict__ x,
                                                      const float* __restrict__ r,
                                                      bf16_t* __restrict__ ws) {
  const int i = blockIdx.x * 256 + threadIdx.x;      // float4 index, total T*D/4
  float4 a = ((const float4*)x)[i];
  float4 b = ((const float4*)r)[i];
  bf16x4 av, bv;
  av[0] = (bf16_t)a.x; av[1] = (bf16_t)a.y; av[2] = (bf16_t)a.z; av[3] = (bf16_t)a.w;
  bv[0] = (bf16_t)b.x; bv[1] = (bf16_t)b.y; bv[2] = (bf16_t)b.z; bv[3] = (bf16_t)b.w;
  ((bf16x4*)(ws + OFF_XB))[i] = av;
  ((bf16x4*)(ws + OFF_RB))[i] = bv;
}

// ---------------- prep 2: W[k][n] fp32 -> Wt[n][k] bf16, 5 weights ----------------
__global__ __launch_bounds__(256) void transpose_w_kernel(const float* __restrict__ Wq,
                                                          const float* __restrict__ Wk,
                                                          const float* __restrict__ Wv,
                                                          const float* __restrict__ Wr,
                                                          const float* __restrict__ Wo,
                                                          bf16_t* __restrict__ ws) {
  const int k0 = blockIdx.x * 64, n0 = blockIdx.y * 64, wsel = blockIdx.z;
  const float* W = (wsel == 0) ? Wq : (wsel == 1) ? Wk : (wsel == 2) ? Wv : (wsel == 3) ? Wr : Wo;
  bf16_t* Wt = ws + OFF_WT + (size_t)wsel * SZ_W;
  __shared__ float tile[64][65];
  const int tid = threadIdx.x;
#pragma unroll
  for (int it = 0; it < 4; ++it) {
    int g = tid + it * 256; int rr = g >> 4; int c4 = (g & 15) * 4;
    float4 v = *(const float4*)&W[(size_t)(k0 + rr) * DDIM + n0 + c4];
    tile[rr][c4] = v.x; tile[rr][c4 + 1] = v.y; tile[rr][c4 + 2] = v.z; tile[rr][c4 + 3] = v.w;
  }
  __syncthreads();
#pragma unroll
  for (int it = 0; it < 4; ++it) {
    int g = tid + it * 256; int nr = g >> 4; int c4 = (g & 15) * 4;
    bf16x4 o;
    o[0] = (bf16_t)tile[c4 + 0][nr]; o[1] = (bf16_t)tile[c4 + 1][nr];
    o[2] = (bf16_t)tile[c4 + 2][nr]; o[3] = (bf16_t)tile[c4 + 3][nr];
    *(bf16x4*)&Wt[(size_t)(n0 + nr) * DDIM + k0 + c4] = o;
  }
}

// ---------------- shared 128x128 GEMM core: C = A[M][K] @ Bt[N][K]^T, K=1024 ----------------
// block = 256 threads = 4 waves (2x2 over the 128x128 tile), 16x16x32 bf16 MFMA.
__device__ __forceinline__ void gemm128_core(const bf16_t* __restrict__ A,
                                             const bf16_t* __restrict__ Bt,
                                             int i0, int n0,
                                             f32x4 acc[4][4],
                                             bf16_t* As, bf16_t* Bs) {
  const int tid = threadIdx.x, lane = tid & 63, wv = tid >> 6;
  const int wr = (wv >> 1) * 64, wc = (wv & 1) * 64;
  const int sr = tid >> 2, scc = (tid & 3) * 8;
  const int l15 = lane & 15, lg8 = (lane >> 4) * 8;
  for (int k0 = 0; k0 < DDIM; k0 += 32) {
    int4 a0 = *(const int4*)&A[(size_t)(i0 + sr) * DDIM + k0 + scc];
    int4 a1 = *(const int4*)&A[(size_t)(i0 + 64 + sr) * DDIM + k0 + scc];
    int4 b0 = *(const int4*)&Bt[(size_t)(n0 + sr) * DDIM + k0 + scc];
    int4 b1 = *(const int4*)&Bt[(size_t)(n0 + 64 + sr) * DDIM + k0 + scc];
    __syncthreads();
    *(int4*)&As[sr * 32 + scc] = a0;
    *(int4*)&As[(64 + sr) * 32 + scc] = a1;
    *(int4*)&Bs[sr * 32 + scc] = b0;
    *(int4*)&Bs[(64 + sr) * 32 + scc] = b1;
    __syncthreads();
    bf16x8 af[4], bfv[4];
#pragma unroll
    for (int m = 0; m < 4; ++m) af[m] = *(const bf16x8*)&As[(wr + m * 16 + l15) * 32 + lg8];
#pragma unroll
    for (int n = 0; n < 4; ++n) bfv[n] = *(const bf16x8*)&Bs[(wc + n * 16 + l15) * 32 + lg8];
#pragma unroll
    for (int m = 0; m < 4; ++m)
#pragma unroll
      for (int n = 0; n < 4; ++n)
        acc[m][n] = __builtin_amdgcn_mfma_f32_16x16x32_bf16(af[m], bfv[n], acc[m][n], 0, 0, 0);
  }
}

// ---------------- projections: z=0 Q(->Qu,Qv), 1 K, 2 V(->Vt), 3 R(->Rrev) ----------------
__global__ __launch_bounds__(256) void proj_kernel(const bf16_t* wsc, bf16_t* wsd,
                                                   const float* __restrict__ u,
                                                   const float* __restrict__ vb) {
  const int z = blockIdx.z;
  const int i0 = blockIdx.x * 128, n0 = blockIdx.y * 128;
  const bf16_t* A = wsc + ((z == 3) ? OFF_RB : OFF_XB);
  const bf16_t* Bt = wsc + OFF_WT + (size_t)z * SZ_W;
  __shared__ bf16_t As[128 * 32];
  __shared__ bf16_t Bs[128 * 32];
  const int lane = threadIdx.x & 63, wv = threadIdx.x >> 6;
  const int wr = (wv >> 1) * 64, wc = (wv & 1) * 64;
  const int l15 = lane & 15, lr4 = (lane >> 4) * 4;
  f32x4 acc[4][4];
#pragma unroll
  for (int m = 0; m < 4; ++m)
#pragma unroll
    for (int n = 0; n < 4; ++n) acc[m][n] = fzero4();

  gemm128_core(A, Bt, i0, n0, acc, As, Bs);

#pragma unroll
  for (int mm = 0; mm < 4; ++mm)
#pragma unroll
    for (int nn = 0; nn < 4; ++nn)
#pragma unroll
      for (int rg = 0; rg < 4; ++rg) {
        const int row = i0 + wr + mm * 16 + lr4 + rg;
        const int col = n0 + wc + nn * 16 + l15;
        const float val = acc[mm][nn][rg];
        const int hh = col >> 6, dh = col & 63;
        if (z == 0) {
          wsd[OFF_QU + ((size_t)hh * TT + row) * 64 + dh] = (bf16_t)(val + u[col]);
          wsd[OFF_QV + ((size_t)hh * TT + row) * 64 + dh] = (bf16_t)(val + vb[col]);
        } else if (z == 1) {
          wsd[OFF_KK + ((size_t)hh * TT + row) * 64 + dh] = (bf16_t)val;
        } else if (z == 2) {
          wsd[OFF_VT + ((size_t)hh * 64 + dh) * TT + row] = (bf16_t)val;
        } else {
          wsd[OFF_RR + ((size_t)hh * TT + (TT - 1 - row)) * 64 + dh] = (bf16_t)val;
        }
      }
}

// ---------------- fused XL attention (flash, causal, rel-shift as banded GEMM) ----------------
__global__ __launch_bounds__(256) void attn_kernel(const bf16_t* wsc, bf16_t* wsd) {
  const int h = blockIdx.y;
  const int qt = 31 - blockIdx.x;          // longest blocks first
  const int i0 = qt * 64;
  const int tid = threadIdx.x;
  const int lane = tid & 63;
  const int wv = tid >> 6;                 // wave owns 16 query rows
  const int iw0 = i0 + wv * 16;
  const int l15 = lane & 15;
  const int lg = lane >> 4;
  const int lg8 = lg * 8;

  const bf16_t* QUp = wsc + OFF_QU + (size_t)h * TT * 64;
  const bf16_t* QVp = wsc + OFF_QV + (size_t)h * TT * 64;
  const bf16_t* Kp  = wsc + OFF_KK + (size_t)h * TT * 64;
  const bf16_t* Rp  = wsc + OFF_RR + (size_t)h * TT * 64;
  const bf16_t* Vp  = wsc + OFF_VT + (size_t)h * 64 * TT;

  __shared__ float Pband[4][16][80];       // per-wave BD band
  __shared__ bf16_t Plds[4][16][72];       // per-wave P (stride 72 = 16B aligned, conflict-light)

  bf16x8 qu[2], qv[2];
#pragma unroll
  for (int ks = 0; ks < 2; ++ks) {
    qu[ks] = *(const bf16x8*)&QUp[(size_t)(iw0 + l15) * 64 + ks * 32 + lg8];
    qv[ks] = *(const bf16x8*)&QVp[(size_t)(iw0 + l15) * 64 + ks * 32 + lg8];
  }

  f32x4 o[4];
#pragma unroll
  for (int d = 0; d < 4; ++d) o[d] = fzero4();
  float mrun[4], lrun[4];
#pragma unroll
  for (int rg = 0; rg < 4; ++rg) { mrun[rg] = -3e38f; lrun[rg] = 0.f; }

  for (int j0 = 0; j0 <= i0; j0 += 64) {
    // ---- AC = (q+u) @ K^T ----
    f32x4 ac[4];
#pragma unroll
    for (int nt = 0; nt < 4; ++nt) ac[nt] = fzero4();
#pragma unroll
    for (int nt = 0; nt < 4; ++nt)
#pragma unroll
      for (int ks = 0; ks < 2; ++ks) {
        bf16x8 kf = *(const bf16x8*)&Kp[(size_t)(j0 + nt * 16 + l15) * 64 + ks * 32 + lg8];
        ac[nt] = __builtin_amdgcn_mfma_f32_16x16x32_bf16(qu[ks], kf, ac[nt], 0, 0, 0);
      }

    // ---- BD band: P[ii][p] = (q+v) . Rrev[c0+p], c0 = iw0-j0-63 ----
    f32x4 bd[5];
#pragma unroll
    for (int bt = 0; bt < 5; ++bt) bd[bt] = fzero4();
    const int c0 = iw0 - j0 - 63;
#pragma unroll
    for (int bt = 0; bt < 5; ++bt) {
      int c = c0 + bt * 16 + l15;
      c = (c < 0) ? 0 : ((c > TT - 1) ? TT - 1 : c);   // clamped rows feed only masked cells
#pragma unroll
      for (int ks = 0; ks < 2; ++ks) {
        bf16x8 rf = *(const bf16x8*)&Rp[(size_t)c * 64 + ks * 32 + lg8];
        bd[bt] = __builtin_amdgcn_mfma_f32_16x16x32_bf16(qv[ks], rf, bd[bt], 0, 0, 0);
      }
    }
#pragma unroll
    for (int bt = 0; bt < 5; ++bt)
#pragma unroll
      for (int rg = 0; rg < 4; ++rg)
        Pband[wv][lg * 4 + rg][bt * 16 + l15] = bd[bt][rg];

    // ---- scores = (AC + BDshift)/8, causal mask ----
    float sc[4][4];
#pragma unroll
    for (int nt = 0; nt < 4; ++nt)
#pragma unroll
      for (int rg = 0; rg < 4; ++rg) {
        const int ii = lg * 4 + rg;
        const int jj = nt * 16 + l15;
        float v = (ac[nt][rg] + Pband[wv][ii][ii - jj + 63]) * 0.125f;
        if (j0 + jj > iw0 + ii) v = -1e30f;
        sc[nt][rg] = v;
      }

    // ---- online softmax (4 rows per lane, reduce within 16-lane groups) ----
#pragma unroll
    for (int rg = 0; rg < 4; ++rg) {
      float rmax = fmaxf(fmaxf(sc[0][rg], sc[1][rg]), fmaxf(sc[2][rg], sc[3][rg]));
      rmax = fmaxf(rmax, __shfl_xor(rmax, 1));
      rmax = fmaxf(rmax, __shfl_xor(rmax, 2));
      rmax = fmaxf(rmax, __shfl_xor(rmax, 4));
      rmax = fmaxf(rmax, __shfl_xor(rmax, 8));
      const float newm = fmaxf(mrun[rg], rmax);
      const float fac = expf(mrun[rg] - newm);
      float pv0 = expf(sc[0][rg] - newm);
      float pv1 = expf(sc[1][rg] - newm);
      float pv2 = expf(sc[2][rg] - newm);
      float pv3 = expf(sc[3][rg] - newm);
      float rsum = pv0 + pv1 + pv2 + pv3;
      rsum += __shfl_xor(rsum, 1);
      rsum += __shfl_xor(rsum, 2);
      rsum += __shfl_xor(rsum, 4);
      rsum += __shfl_xor(rsum, 8);
      lrun[rg] = lrun[rg] * fac + rsum;
      mrun[rg] = newm;
#pragma unroll
      for (int d = 0; d < 4; ++d) o[d][rg] *= fac;
      const int ii = lg * 4 + rg;
      Plds[wv][ii][0 * 16 + l15] = (bf16_t)pv0;
      Plds[wv][ii][1 * 16 + l15] = (bf16_t)pv1;
      Plds[wv][ii][2 * 16 + l15] = (bf16_t)pv2;
      Plds[wv][ii][3 * 16 + l15] = (bf16_t)pv3;
    }

    // ---- PV: O += P @ V (V pre-transposed: Vt[dh][t]) ----
    bf16x8 pf[2];
#pragma unroll
    for (int ks = 0; ks < 2; ++ks)
      pf[ks] = *(const bf16x8*)&Plds[wv][l15][ks * 32 + lg8];
#pragma unroll
    for (int d = 0; d < 4; ++d)
#pragma unroll
      for (int ks = 0; ks < 2; ++ks) {
        bf16x8 vf = *(const bf16x8*)&Vp[(size_t)(d * 16 + l15) * TT + j0 + ks * 32 + lg8];
        o[d] = __builtin_amdgcn_mfma_f32_16x16x32_bf16(pf[ks], vf, o[d], 0, 0, 0);
      }
  }

  // ---- epilogue: attnout[t][h*64+dh] = O / l ----
#pragma unroll
  for (int d = 0; d < 4; ++d)
#pragma unroll
    for (int rg = 0; rg < 4; ++rg) {
      const int row = iw0 + lg * 4 + rg;
      const int col = h * 64 + d * 16 + l15;
      wsd[OFF_AO + (size_t)row * DDIM + col] = (bf16_t)(o[d][rg] / lrun[rg]);
    }
}

// ---------------- output projection: out = attnout @ Wo ----------------
__global__ __launch_bounds__(256) void outproj_kernel(const bf16_t* wsc, float* __restrict__ outp) {
  const int i0 = blockIdx.x * 128, n0 = blockIdx.y * 128;
  const bf16_t* A = wsc + OFF_AO;
  const bf16_t* Bt = wsc + OFF_WT + 4 * SZ_W;
  __shared__ bf16_t As[128 * 32];
  __shared__ bf16_t Bs[128 * 32];
  const int lane = threadIdx.x & 63, wv = threadIdx.x >> 6;
  const int wr = (wv >> 1) * 64, wc = (wv & 1) * 64;
  const int l15 = lane & 15, lr4 = (lane >> 4) * 4;
  f32x4 acc[4][4];
#pragma unroll
  for (int m = 0; m < 4; ++m)
#pragma unroll
    for (int n = 0; n < 4; ++n) acc[m][n] = fzero4();

  gemm128_core(A, Bt, i0, n0, acc, As, Bs);

#pragma unroll
  for (int mm = 0; mm < 4; ++mm)
#pragma unroll
    for (int nn = 0; nn < 4; ++nn)
#pragma unroll
      for (int rg = 0; rg < 4; ++rg) {
        const int row = i0 + wr + mm * 16 + lr4 + rg;
        const int col = n0 + wc + nn * 16 + l15;
        outp[(size_t)row * DDIM + col] = acc[mm][nn][rg];
      }
}

extern "C" void kernel_launch(void* const* d_in, const int* in_sizes, int n_in,
                              void* d_out, int out_size, void* d_ws, size_t ws_size,
                              hipStream_t stream) {
  (void)in_sizes; (void)n_in; (void)out_size; (void)ws_size;
  const float* x    = (const float*)d_in[0];
  const float* remb = (const float*)d_in[1];
  const float* Wq   = (const float*)d_in[2];
  const float* Wk   = (const float*)d_in[3];
  const float* Wv   = (const float*)d_in[4];
  const float* Wr   = (const float*)d_in[5];
  const float* Wo   = (const float*)d_in[6];
  const float* u    = (const float*)d_in[7];
  const float* vb   = (const float*)d_in[8];
  bf16_t* ws = (bf16_t*)d_ws;
  float* outp = (float*)d_out;

  convert_kernel<<<dim3(2048), 256, 0, stream>>>(x, remb, ws);
  transpose_w_kernel<<<dim3(16, 16, 5), 256, 0, stream>>>(Wq, Wk, Wv, Wr, Wo, ws);
  proj_kernel<<<dim3(16, 8, 4), 256, 0, stream>>>(ws, ws, u, vb);
  attn_kernel<<<dim3(32, 16), 256, 0, stream>>>(ws, ws);
  outproj_kernel<<<dim3(16, 8), 256, 0, stream>>>(ws, outp);
}

// Round 3
// 337.621 us; speedup vs baseline: 1.0888x; 1.0888x over previous
//
#include <hip/hip_runtime.h>

typedef __bf16 bf16_t;
typedef __bf16 bf16x4v __attribute__((ext_vector_type(4)));
typedef __bf16 bf16x8 __attribute__((ext_vector_type(8)));
typedef float f32x4 __attribute__((ext_vector_type(4)));

constexpr int TT = 2048;
constexpr int DDIM = 1024;

// workspace layout (bf16 element offsets)
constexpr size_t SZ_TD  = (size_t)2048 * 1024;
constexpr size_t OFF_QU = 0;                     // Qu[h][t][dh] = q + u
constexpr size_t OFF_QV = 1 * SZ_TD;             // Qv[h][t][dh] = q + v_bias
constexpr size_t OFF_KK = 2 * SZ_TD;             // K [h][t][dh]
constexpr size_t OFF_RR = 3 * SZ_TD;             // Rrev[h][c][dh] = R[T-1-c]
constexpr size_t OFF_VT = 4 * SZ_TD;             // Vt[h][dh][t]
constexpr size_t OFF_AO = 5 * SZ_TD;             // attnout[t][d]
constexpr size_t OFF_XB = 6 * SZ_TD;             // x bf16 [t][d]
constexpr size_t OFF_RB = 7 * SZ_TD;             // r_emb bf16 [t][d]
constexpr size_t OFF_WT = 8 * SZ_TD;             // Wt[5][n][k] bf16 (q,k,v,r,o)
constexpr size_t SZ_W   = (size_t)1024 * 1024;

__device__ __forceinline__ f32x4 fzero4() {
  f32x4 z; z[0] = 0.f; z[1] = 0.f; z[2] = 0.f; z[3] = 0.f; return z;
}

__device__ __forceinline__ void gload16(const bf16_t* g, bf16_t* l) {
  __builtin_amdgcn_global_load_lds((const __attribute__((address_space(1))) void*)g,
                                   (__attribute__((address_space(3))) void*)l, 16, 0, 0);
}

// ---------------- prep 1: fp32 -> bf16 for x and r_emb ----------------
__global__ __launch_bounds__(256) void convert_kernel(const float* __restrict__ x,
                                                      const float* __restrict__ r,
                                                      bf16_t* __restrict__ ws) {
  const int i = blockIdx.x * 256 + threadIdx.x;
  float4 a = ((const float4*)x)[i];
  float4 b = ((const float4*)r)[i];
  bf16x4v av, bv;
  av[0] = (bf16_t)a.x; av[1] = (bf16_t)a.y; av[2] = (bf16_t)a.z; av[3] = (bf16_t)a.w;
  bv[0] = (bf16_t)b.x; bv[1] = (bf16_t)b.y; bv[2] = (bf16_t)b.z; bv[3] = (bf16_t)b.w;
  ((bf16x4v*)(ws + OFF_XB))[i] = av;
  ((bf16x4v*)(ws + OFF_RB))[i] = bv;
}

// ---------------- prep 2: W[k][n] fp32 -> Wt[n][k] bf16, 5 weights ----------------
__global__ __launch_bounds__(256) void transpose_w_kernel(const float* __restrict__ Wq,
                                                          const float* __restrict__ Wk,
                                                          const float* __restrict__ Wv,
                                                          const float* __restrict__ Wr,
                                                          const float* __restrict__ Wo,
                                                          bf16_t* __restrict__ ws) {
  const int k0 = blockIdx.x * 64, n0 = blockIdx.y * 64, wsel = blockIdx.z;
  const float* W = (wsel == 0) ? Wq : (wsel == 1) ? Wk : (wsel == 2) ? Wv : (wsel == 3) ? Wr : Wo;
  bf16_t* Wt = ws + OFF_WT + (size_t)wsel * SZ_W;
  __shared__ float tile[64][65];
  const int tid = threadIdx.x;
#pragma unroll
  for (int it = 0; it < 4; ++it) {
    int g = tid + it * 256; int rr = g >> 4; int c4 = (g & 15) * 4;
    float4 v = *(const float4*)&W[(size_t)(k0 + rr) * DDIM + n0 + c4];
    tile[rr][c4] = v.x; tile[rr][c4 + 1] = v.y; tile[rr][c4 + 2] = v.z; tile[rr][c4 + 3] = v.w;
  }
  __syncthreads();
#pragma unroll
  for (int it = 0; it < 4; ++it) {
    int g = tid + it * 256; int nr = g >> 4; int c4 = (g & 15) * 4;
    bf16x4v o;
    o[0] = (bf16_t)tile[c4 + 0][nr]; o[1] = (bf16_t)tile[c4 + 1][nr];
    o[2] = (bf16_t)tile[c4 + 2][nr]; o[3] = (bf16_t)tile[c4 + 3][nr];
    *(bf16x4v*)&Wt[(size_t)(n0 + nr) * DDIM + k0 + c4] = o;
  }
}

// ---------------- shared 128x128 GEMM core (global_load_lds staging, m97-style) -------------
__device__ __forceinline__ void gemm128_core(const bf16_t* __restrict__ A,
                                             const bf16_t* __restrict__ Bt,
                                             int i0, int n0,
                                             f32x4 acc[4][4],
                                             bf16_t* As, bf16_t* Bs) {
  const int tid = threadIdx.x, lane = tid & 63, wv = tid >> 6;
  const int wr = (wv >> 1) * 64, wc = (wv & 1) * 64;
  const int sr = tid >> 2, scc = (tid & 3) * 8;      // As dest elem = tid*8 (linear, 16B/lane)
  const int l15 = lane & 15, lg8 = (lane >> 4) * 8;
  for (int k0 = 0; k0 < DDIM; k0 += 32) {
    __syncthreads();   // previous iter's frag reads done before overwrite
    gload16(&A[(size_t)(i0 + sr) * DDIM + k0 + scc],       &As[sr * 32 + scc]);
    gload16(&A[(size_t)(i0 + 64 + sr) * DDIM + k0 + scc],  &As[(64 + sr) * 32 + scc]);
    gload16(&Bt[(size_t)(n0 + sr) * DDIM + k0 + scc],      &Bs[sr * 32 + scc]);
    gload16(&Bt[(size_t)(n0 + 64 + sr) * DDIM + k0 + scc], &Bs[(64 + sr) * 32 + scc]);
    __syncthreads();   // drains vmcnt(0) (gload_lds) + barrier
    bf16x8 af[4], bfv[4];
#pragma unroll
    for (int m = 0; m < 4; ++m) af[m] = *(const bf16x8*)&As[(wr + m * 16 + l15) * 32 + lg8];
#pragma unroll
    for (int n = 0; n < 4; ++n) bfv[n] = *(const bf16x8*)&Bs[(wc + n * 16 + l15) * 32 + lg8];
#pragma unroll
    for (int m = 0; m < 4; ++m)
#pragma unroll
      for (int n = 0; n < 4; ++n)
        acc[m][n] = __builtin_amdgcn_mfma_f32_16x16x32_bf16(af[m], bfv[n], acc[m][n], 0, 0, 0);
  }
}

// ---------------- projections: z=0 Q(->Qu,Qv), 1 K, 2 V(->Vt), 3 R(->Rrev) ----------------
__global__ __launch_bounds__(256) void proj_kernel(const bf16_t* wsc, bf16_t* wsd,
                                                   const float* __restrict__ u,
                                                   const float* __restrict__ vb) {
  const int z = blockIdx.z;
  const int i0 = blockIdx.x * 128, n0 = blockIdx.y * 128;
  const bf16_t* A = wsc + ((z == 3) ? OFF_RB : OFF_XB);
  const bf16_t* Bt = wsc + OFF_WT + (size_t)z * SZ_W;
  __shared__ bf16_t As[128 * 32];
  __shared__ bf16_t Bs[128 * 32];
  const int lane = threadIdx.x & 63, wv = threadIdx.x >> 6;
  const int wr = (wv >> 1) * 64, wc = (wv & 1) * 64;
  const int l15 = lane & 15, lr4 = (lane >> 4) * 4;
  f32x4 acc[4][4];
#pragma unroll
  for (int m = 0; m < 4; ++m)
#pragma unroll
    for (int n = 0; n < 4; ++n) acc[m][n] = fzero4();

  gemm128_core(A, Bt, i0, n0, acc, As, Bs);

#pragma unroll
  for (int mm = 0; mm < 4; ++mm)
#pragma unroll
    for (int nn = 0; nn < 4; ++nn)
#pragma unroll
      for (int rg = 0; rg < 4; ++rg) {
        const int row = i0 + wr + mm * 16 + lr4 + rg;
        const int col = n0 + wc + nn * 16 + l15;
        const float val = acc[mm][nn][rg];
        const int hh = col >> 6, dh = col & 63;
        if (z == 0) {
          wsd[OFF_QU + ((size_t)hh * TT + row) * 64 + dh] = (bf16_t)(val + u[col]);
          wsd[OFF_QV + ((size_t)hh * TT + row) * 64 + dh] = (bf16_t)(val + vb[col]);
        } else if (z == 1) {
          wsd[OFF_KK + ((size_t)hh * TT + row) * 64 + dh] = (bf16_t)val;
        } else if (z == 2) {
          wsd[OFF_VT + ((size_t)hh * 64 + dh) * TT + row] = (bf16_t)val;
        } else {
          wsd[OFF_RR + ((size_t)hh * TT + (TT - 1 - row)) * 64 + dh] = (bf16_t)val;
        }
      }
}

// ---------------- fused XL attention: swapped-QKT flash, K reg-double-buffered -------------
// 2 waves/block, 32 q-rows/block, grid (64, 16). Lane holds 16 scores of q-row (lane&15).
#define LOADK(DST, JJ)                                                                     \
  _Pragma("unroll") for (int nt_ = 0; nt_ < 4; ++nt_)                                      \
  _Pragma("unroll") for (int ks_ = 0; ks_ < 2; ++ks_)                                      \
    DST[nt_][ks_] = *(const bf16x8*)&Kp[(size_t)((JJ) + nt_ * 16 + l15) * 64 + ks_ * 32 + lg8];

#define ATTN_BODY(KC, KN, J0, JN)                                                          \
  {                                                                                        \
    bf16x8 rf[5][2];                                                                       \
    const int c0 = iw0 - (J0) - 63;                                                        \
    _Pragma("unroll") for (int bt = 0; bt < 5; ++bt) {                                     \
      int c = c0 + bt * 16 + l15;                                                          \
      c = (c < 0) ? 0 : ((c > TT - 1) ? TT - 1 : c);                                       \
      _Pragma("unroll") for (int ks = 0; ks < 2; ++ks)                                     \
        rf[bt][ks] = *(const bf16x8*)&Rp[(size_t)c * 64 + ks * 32 + lg8];                  \
    }                                                                                      \
    bf16x8 vf[4][2];                                                                       \
    _Pragma("unroll") for (int d = 0; d < 4; ++d)                                          \
      _Pragma("unroll") for (int ks = 0; ks < 2; ++ks)                                     \
        vf[d][ks] = *(const bf16x8*)&Vp[(size_t)(d * 16 + l15) * TT + (J0) + ks * 32 + lg8];\
    LOADK(KN, JN)                                                                          \
    f32x4 ac[4];                                                                           \
    _Pragma("unroll") for (int nt = 0; nt < 4; ++nt) ac[nt] = fzero4();                    \
    _Pragma("unroll") for (int nt = 0; nt < 4; ++nt)                                       \
      _Pragma("unroll") for (int ks = 0; ks < 2; ++ks)                                     \
        ac[nt] = __builtin_amdgcn_mfma_f32_16x16x32_bf16(KC[nt][ks], qu[ks], ac[nt], 0, 0, 0); \
    f32x4 bd[5];                                                                           \
    _Pragma("unroll") for (int bt = 0; bt < 5; ++bt) bd[bt] = fzero4();                    \
    _Pragma("unroll") for (int bt = 0; bt < 5; ++bt)                                       \
      _Pragma("unroll") for (int ks = 0; ks < 2; ++ks)                                     \
        bd[bt] = __builtin_amdgcn_mfma_f32_16x16x32_bf16(rf[bt][ks], qv[ks], bd[bt], 0, 0, 0); \
    _Pragma("unroll") for (int bt = 0; bt < 5; ++bt)                                       \
      _Pragma("unroll") for (int rg = 0; rg < 4; ++rg)                                     \
        PB[(bt * 16 + lg * 4 + rg) * 17 + l15] = bd[bt][rg];                               \
    float sc[4][4];                                                                        \
    float smax = -3e38f;                                                                   \
    _Pragma("unroll") for (int nt = 0; nt < 4; ++nt)                                       \
      _Pragma("unroll") for (int rg = 0; rg < 4; ++rg) {                                   \
        const int jj = nt * 16 + lg * 4 + rg;                                              \
        float v = (ac[nt][rg] + PB[(l15 + 63 - jj) * 17 + l15]) * 0.125f;                  \
        v = ((J0) + jj > iw0 + l15) ? -1e30f : v;                                          \
        smax = fmaxf(smax, v);                                                             \
        sc[nt][rg] = v;                                                                    \
      }                                                                                    \
    smax = fmaxf(smax, __shfl_xor(smax, 16));                                              \
    smax = fmaxf(smax, __shfl_xor(smax, 32));                                              \
    const float newm = fmaxf(mrun, smax);                                                  \
    const float fac = __expf(mrun - newm);                                                 \
    mrun = newm;                                                                           \
    float pv[4][4];                                                                        \
    float rsum = 0.f;                                                                      \
    _Pragma("unroll") for (int nt = 0; nt < 4; ++nt)                                       \
      _Pragma("unroll") for (int rg = 0; rg < 4; ++rg) {                                   \
        pv[nt][rg] = __expf(sc[nt][rg] - newm);                                            \
        rsum += pv[nt][rg];                                                                \
      }                                                                                    \
    rsum += __shfl_xor(rsum, 16);                                                          \
    rsum += __shfl_xor(rsum, 32);                                                          \
    lrun = lrun * fac + rsum;                                                              \
    float fo[4];                                                                           \
    _Pragma("unroll") for (int rg = 0; rg < 4; ++rg) fo[rg] = __shfl(fac, lg * 4 + rg);    \
    _Pragma("unroll") for (int d = 0; d < 4; ++d)                                          \
      _Pragma("unroll") for (int rg = 0; rg < 4; ++rg) o[d][rg] *= fo[rg];                 \
    _Pragma("unroll") for (int nt = 0; nt < 4; ++nt) {                                     \
      bf16x4v pk;                                                                          \
      pk[0] = (bf16_t)pv[nt][0]; pk[1] = (bf16_t)pv[nt][1];                                \
      pk[2] = (bf16_t)pv[nt][2]; pk[3] = (bf16_t)pv[nt][3];                                \
      *(bf16x4v*)&PL[l15 * 72 + nt * 16 + lg * 4] = pk;                                    \
    }                                                                                      \
    bf16x8 pf[2];                                                                          \
    _Pragma("unroll") for (int ks = 0; ks < 2; ++ks)                                       \
      pf[ks] = *(const bf16x8*)&PL[l15 * 72 + ks * 32 + lg8];                              \
    _Pragma("unroll") for (int d = 0; d < 4; ++d)                                          \
      _Pragma("unroll") for (int ks = 0; ks < 2; ++ks)                                     \
        o[d] = __builtin_amdgcn_mfma_f32_16x16x32_bf16(pf[ks], vf[d][ks], o[d], 0, 0, 0);  \
  }

__global__ __launch_bounds__(128) void attn_kernel(const bf16_t* wsc, bf16_t* wsd) {
  const int h = blockIdx.y;
  const int q32 = 63 - blockIdx.x;         // longest blocks first
  const int i0 = q32 * 32;
  const int tid = threadIdx.x;
  const int lane = tid & 63;
  const int wv = tid >> 6;                 // wave owns 16 q-rows
  const int iw0 = i0 + wv * 16;
  const int l15 = lane & 15;
  const int lg = lane >> 4;
  const int lg8 = lg * 8;
  const int J = (i0 >> 6) << 6;            // last 64-col j-tile base

  const bf16_t* QUp = wsc + OFF_QU + (size_t)h * TT * 64;
  const bf16_t* QVp = wsc + OFF_QV + (size_t)h * TT * 64;
  const bf16_t* Kp  = wsc + OFF_KK + (size_t)h * TT * 64;
  const bf16_t* Rp  = wsc + OFF_RR + (size_t)h * TT * 64;
  const bf16_t* Vp  = wsc + OFF_VT + (size_t)h * 64 * TT;

  __shared__ float PbandS[2][80 * 17];     // band, stride 17 -> conflict-free reads
  __shared__ bf16_t PldsS[2][16 * 72];     // P rows, stride 72 elems (16B aligned)
  float* PB = PbandS[wv];
  bf16_t* PL = PldsS[wv];

  bf16x8 qu[2], qv[2];
#pragma unroll
  for (int ks = 0; ks < 2; ++ks) {
    qu[ks] = *(const bf16x8*)&QUp[(size_t)(iw0 + l15) * 64 + ks * 32 + lg8];
    qv[ks] = *(const bf16x8*)&QVp[(size_t)(iw0 + l15) * 64 + ks * 32 + lg8];
  }

  f32x4 o[4];
#pragma unroll
  for (int d = 0; d < 4; ++d) o[d] = fzero4();
  float mrun = -3e38f, lrun = 0.f;

  bf16x8 kA[4][2], kB[4][2];
  LOADK(kA, 0)

  int j0 = 0;
  while (true) {
    int jn = j0 + 64; if (jn > J) jn = J;
    ATTN_BODY(kA, kB, j0, jn)
    if (j0 >= J) break;
    j0 += 64;
    jn = j0 + 64; if (jn > J) jn = J;
    ATTN_BODY(kB, kA, j0, jn)
    if (j0 >= J) break;
    j0 += 64;
  }

  // epilogue: attnout[t][h*64+dh] = O / l   (o row = lg*4+rg, col = d*16+l15)
  float lq[4];
#pragma unroll
  for (int rg = 0; rg < 4; ++rg) lq[rg] = __shfl(lrun, lg * 4 + rg);
#pragma unroll
  for (int d = 0; d < 4; ++d)
#pragma unroll
    for (int rg = 0; rg < 4; ++rg) {
      const int row = iw0 + lg * 4 + rg;
      const int col = h * 64 + d * 16 + l15;
      wsd[OFF_AO + (size_t)row * DDIM + col] = (bf16_t)(o[d][rg] / lq[rg]);
    }
}

// ---------------- output projection: out = attnout @ Wo ----------------
__global__ __launch_bounds__(256) void outproj_kernel(const bf16_t* wsc, float* __restrict__ outp) {
  const int i0 = blockIdx.x * 128, n0 = blockIdx.y * 128;
  const bf16_t* A = wsc + OFF_AO;
  const bf16_t* Bt = wsc + OFF_WT + 4 * SZ_W;
  __shared__ bf16_t As[128 * 32];
  __shared__ bf16_t Bs[128 * 32];
  const int lane = threadIdx.x & 63, wv = threadIdx.x >> 6;
  const int wr = (wv >> 1) * 64, wc = (wv & 1) * 64;
  const int l15 = lane & 15, lr4 = (lane >> 4) * 4;
  f32x4 acc[4][4];
#pragma unroll
  for (int m = 0; m < 4; ++m)
#pragma unroll
    for (int n = 0; n < 4; ++n) acc[m][n] = fzero4();

  gemm128_core(A, Bt, i0, n0, acc, As, Bs);

#pragma unroll
  for (int mm = 0; mm < 4; ++mm)
#pragma unroll
    for (int nn = 0; nn < 4; ++nn)
#pragma unroll
      for (int rg = 0; rg < 4; ++rg) {
        const int row = i0 + wr + mm * 16 + lr4 + rg;
        const int col = n0 + wc + nn * 16 + l15;
        outp[(size_t)row * DDIM + col] = acc[mm][nn][rg];
      }
}

extern "C" void kernel_launch(void* const* d_in, const int* in_sizes, int n_in,
                              void* d_out, int out_size, void* d_ws, size_t ws_size,
                              hipStream_t stream) {
  (void)in_sizes; (void)n_in; (void)out_size; (void)ws_size;
  const float* x    = (const float*)d_in[0];
  const float* remb = (const float*)d_in[1];
  const float* Wq   = (const float*)d_in[2];
  const float* Wk   = (const float*)d_in[3];
  const float* Wv   = (const float*)d_in[4];
  const float* Wr   = (const float*)d_in[5];
  const float* Wo   = (const float*)d_in[6];
  const float* u    = (const float*)d_in[7];
  const float* vb   = (const float*)d_in[8];
  bf16_t* ws = (bf16_t*)d_ws;
  float* outp = (float*)d_out;

  convert_kernel<<<dim3(2048), 256, 0, stream>>>(x, remb, ws);
  transpose_w_kernel<<<dim3(16, 16, 5), 256, 0, stream>>>(Wq, Wk, Wv, Wr, Wo, ws);
  proj_kernel<<<dim3(16, 8, 4), 256, 0, stream>>>(ws, ws, u, vb);
  attn_kernel<<<dim3(64, 16), 128, 0, stream>>>(ws, ws);
  outproj_kernel<<<dim3(16, 8), 256, 0, stream>>>(ws, outp);
}